// Round 4
// baseline (113.265 us; speedup 1.0000x reference)
//
#include <hip/hip_runtime.h>

// Problem constants (from reference)
constexpr int L  = 250;   // layers
constexpr int T  = 600;   // traces
constexpr int A  = 30;    // angles

typedef _Float16 h8  __attribute__((ext_vector_type(8)));   // MFMA A/B frag (4 VGPR)
typedef _Float16 h4  __attribute__((ext_vector_type(4)));   // staged A half-frag
typedef float    f4  __attribute__((ext_vector_type(4)));   // MFMA C/D frag

// LDS row strides (halfs): 264 = 256+8 -> 16-B aligned rows, bank-spread
constexpr int RT_LD = 264;
constexpr int WA_LD = 264;

// ---------------- R18: STRICT BISECT - R12 + monolithic pre-staged wm --------
// R16 (dbuf pipeline) and R17 (single-buf pipeline) both FAILED with the same
// ~0.065 absmax despite layout algebra verifying correct 3x. Both shared the
// per-K-step staging pipeline; R12 (proven twice, 41.8 us) had none. R18
// bisects: R12 source byte-identical EXCEPT wm is staged to LDS ONCE, before
// the one barrier R12 already has.
//   * No new barriers, no double buffer, no prefetch registers: staging
//     writes (wmA) and phase-1 writes (refT) are disjoint LDS, both complete
//     before the existing __syncthreads; K-loop reads only.
//   * Staged values reproduce R12's A-fragments BIT-EXACTLY: row clamp to
//     249 for rows>=250, zero-select for cols>=250, RNE f32->f16. The MFMA
//     input stream is therefore identical to the proven kernel; only the
//     transport changes (global lane->row gather -> ds_read_b128).
//   * L1-scatter theory (untimed in R16/R17): old A-path = lane->row loads
//     1000 B apart = 64 lines/wave-instr, ~32K line-req/block ~= whole 100K
//     cycle duration. Now: staging is (8 rows x 32-col) coalesced wave
//     accesses (~8K line-req/block), K-loop has ZERO global traffic.
//   * LDS 149 KB -> 1 block/CU (4 waves). Occupancy sacrificed for the
//     bisect; re-add once staging is proven sound.
// NO workspace, NO producer kernel (R8-R11 non-deterministic handoff).
__global__ __launch_bounds__(256)
void zoep_fused(const float* __restrict__ vp,
                const float* __restrict__ vs,
                const float* __restrict__ rho,
                const float* __restrict__ theta,
                const float* __restrict__ wm,
                float* __restrict__ out)
{
    __shared__ alignas(16) _Float16 refT[32 * RT_LD];    // 16.9 KB: refT[a][k]
    __shared__ alignas(16) _Float16 wmA[256 * WA_LD];    // 132 KB: wmA[m][k] (f16)
    __shared__ float sth_s[32];
    __shared__ float cth_s[32];

    const int tid = threadIdx.x;
    const int t   = blockIdx.x;

    if (tid < 32) {
        const float th = (tid < A) ? theta[tid] : 0.0f;
        sth_s[tid] = sinf(th);
        cth_s[tid] = cosf(th);
    }
    __syncthreads();

    // ---- Phase 1: thread owns interface k = tid (0..255) ---- (R12 verbatim)
    const int  k     = tid;
    const bool valid = (k < L - 1);
    const int  kc    = valid ? k : (L - 2);   // clamped: loads always in-bounds

    const float a1 = vp[kc * T + t];          // lane-distinct lines, 1 instr/array
    const float a2 = vp[(kc + 1) * T + t];
    const float b1 = vs[kc * T + t];
    const float b2 = vs[(kc + 1) * T + t];
    const float r1 = rho[kc * T + t];
    const float r2 = rho[(kc + 1) * T + t];

    const float ra1  = __builtin_amdgcn_rcpf(a1);
    const float rb1  = r1 * b1, rb2 = r2 * b2;
    const float ra1r = r1 * a1, ra2r = r2 * a2;

#pragma unroll 2
    for (int a = 0; a < A; ++a) {
        const float sth = sth_s[a];           // LDS broadcast (uniform a)
        const float cth = cth_s[a];

        const float p   = sth * ra1;
        const float s2  = p * a2;             // |.| <= 0.84 < 1 (input ranges)
        const float c2  = sqrtf(1.0f - s2 * s2);
        const float sp1 = p * b1;
        const float cp1 = sqrtf(1.0f - sp1 * sp1);
        const float sp2 = p * b2;
        const float cp2 = sqrtf(1.0f - sp2 * sp2);

        const float k1 = 1.0f - 2.0f * sp1 * sp1;
        const float k2 = 1.0f - 2.0f * sp2 * sp2;
        const float q1 = rb1 * k1;
        const float q2 = rb2 * k2;
        const float P1 = ra1r * k1;
        const float P2 = ra2r * k2;
        const float u1 = 2.0f * rb1 * sp1;
        const float u2 = 2.0f * rb2 * sp2;
        const float S1 = u1 * cp1;
        const float S2 = u2 * cp2;
        const float g1 = u1 * cth;
        const float g2 = u2 * c2;

        // M (row-major)
        const float m00 = -sth, m01 = -cp1, m02 = s2,  m03 = cp2;
        const float m10 =  cth, m11 = -sp1, m12 = c2,  m13 = -sp2;
        const float m20 =  g1,  m21 =  q1,  m22 = g2,  m23 = q2;
        const float m30 = -P1,  m31 =  S1,  m32 = P2,  m33 = -S2;

        // 2x2 minors: s* rows{0,1}, c* rows{2,3}
        const float s3v = m01 * m12 - m11 * m02;
        const float s4v = m01 * m13 - m11 * m03;
        const float s5v = m02 * m13 - m12 * m03;
        const float c3v = m21 * m32 - m31 * m22;
        const float c4v = m21 * m33 - m31 * m23;
        const float c5v = m22 * m33 - m32 * m23;
        const float s0v = m00 * m11 - m10 * m01;
        const float s1v = m00 * m12 - m10 * m02;
        const float s2v = m00 * m13 - m10 * m03;
        const float c0v = m20 * m31 - m30 * m21;
        const float c1v = m20 * m32 - m30 * m22;
        const float c2v = m20 * m33 - m30 * m23;

        const float detM = s0v*c5v - s1v*c4v + s2v*c3v
                         + s3v*c2v - s4v*c1v + s5v*c0v;
        const float A0 = m11*c5v - m12*c4v + m13*c3v;   // minor(0,0)
        const float A3 = m21*s5v - m22*s4v + m23*s3v;   // minor(3,0)

        const float num = m00 * A0 - m30 * A3;
        const float res = 1.0f - 2.0f * num * __builtin_amdgcn_rcpf(detM);

        refT[a * RT_LD + k] = (_Float16)(valid ? res : 0.0f);
    }
    // zero pad rows a = 30, 31 (column k)
    refT[30 * RT_LD + k] = (_Float16)0.0f;
    refT[31 * RT_LD + k] = (_Float16)0.0f;

    // ---- Stage wm -> wmA (f16), ONCE, before the single barrier --------------
    // wmA[m][c] = R12's A-fragment value: row clamp (m>=250 -> 249), col
    // zero-select (c>=250 -> 0), RNE f32->f16. Thread (cg=tid&7, r0=tid>>3)
    // covers cols cg*4..cg*4+3 of rows r0+32p, all 8 col-steps: coalesced
    // (a wave touches 8 rows x 32-B segments, ~16 lines/instr vs 64 for the
    // old lane->row fragment gather).
    {
        const int cg = tid & 7;
        const int r0 = tid >> 3;
#pragma unroll
        for (int cs = 0; cs < 8; ++cs) {
#pragma unroll
            for (int p = 0; p < 8; ++p) {
                const int r  = p * 32 + r0;
                const int rc = (r < L) ? r : (L - 1);
                const int c0 = cs * 32 + cg * 4;                   // 0..252
                const int c0c = (c0     <= L - 2) ? c0     : (L - 2);
                const int c1c = (c0 + 2 <= L - 2) ? c0 + 2 : (L - 2);
                const float2 f0 = *(const float2*)(wm + rc * L + c0c); // 8-B ok
                const float2 f1 = *(const float2*)(wm + rc * L + c1c);
                h4 v;
                v[0] = (_Float16)((c0     < L) ? f0.x : 0.0f);
                v[1] = (_Float16)((c0 + 1 < L) ? f0.y : 0.0f);
                v[2] = (_Float16)((c0 + 2 < L) ? f1.x : 0.0f);
                v[3] = (_Float16)((c0 + 3 < L) ? f1.y : 0.0f);
                *(h4*)&wmA[r * WA_LD + c0] = v;    // 8-B aligned ds_write_b64
            }
        }
    }
    __syncthreads();   // the one barrier: refT AND wmA published

    // ---- Phase 2: MFMA GEMM, all operands in LDS, no barriers ----------------
    // Verified layouts (R12): A[m=lane&15][k=quad*8+j], B[k=quad*8+j][n=lane&15],
    // C/D[row=quad*4+reg][col=lane&15].
    const int w    = tid >> 6;       // wave 0..3
    const int lane = tid & 63;
    const int quad = lane >> 4;      // 0..3
    const int n16  = lane & 15;

    f4 acc[4][2];
#pragma unroll
    for (int mi = 0; mi < 4; ++mi)
#pragma unroll
        for (int nt = 0; nt < 2; ++nt) acc[mi][nt] = (f4){0.f, 0.f, 0.f, 0.f};

#pragma unroll
    for (int ks = 0; ks < 8; ++ks) {                 // K = 8 x 32
        const int kofs = ks * 32 + quad * 8;
        const h8 b0 = *(const h8*)&refT[ n16       * RT_LD + kofs];
        const h8 b1 = *(const h8*)&refT[(16 + n16) * RT_LD + kofs];
#pragma unroll
        for (int mi = 0; mi < 4; ++mi) {
            const int m = (w * 4 + mi) * 16 + n16;           // 0..255, all staged
            const h8 af = *(const h8*)&wmA[m * WA_LD + kofs]; // 16-B ds_read_b128
            acc[mi][0] = __builtin_amdgcn_mfma_f32_16x16x32_f16(af, b0, acc[mi][0], 0, 0, 0);
            acc[mi][1] = __builtin_amdgcn_mfma_f32_16x16x32_f16(af, b1, acc[mi][1], 0, 0, 0);
        }
    }

    // ---- Epilogue: D[row=quad*4+r][col=n16] -> out[t][l][a] ---- (R12 verbatim)
    float* outt = out + (size_t)t * (L * A);
#pragma unroll
    for (int mi = 0; mi < 4; ++mi) {
        const int mbase = (w * 4 + mi) * 16 + quad * 4;
#pragma unroll
        for (int nt = 0; nt < 2; ++nt) {
            const int a = nt * 16 + n16;
            if (a < A) {
#pragma unroll
                for (int r = 0; r < 4; ++r) {
                    const int l = mbase + r;
                    if (l < L) outt[l * A + a] = acc[mi][nt][r];
                }
            }
        }
    }
}

extern "C" void kernel_launch(void* const* d_in, const int* in_sizes, int n_in,
                              void* d_out, int out_size, void* d_ws, size_t ws_size,
                              hipStream_t stream) {
    (void)in_sizes; (void)n_in; (void)out_size; (void)d_ws; (void)ws_size;
    const float* vp    = (const float*)d_in[0];
    const float* vs    = (const float*)d_in[1];
    const float* rho   = (const float*)d_in[2];
    const float* theta = (const float*)d_in[3];
    const float* wm    = (const float*)d_in[4];
    float* out = (float*)d_out;

    zoep_fused<<<dim3(T), dim3(256), 0, stream>>>(vp, vs, rho, theta, wm, out);
}

// Round 6
// 112.786 us; speedup vs baseline: 1.0042x; 1.0042x over previous
//
#include <hip/hip_runtime.h>

// Problem constants (from reference)
constexpr int L  = 250;   // layers
constexpr int T  = 600;   // traces
constexpr int A  = 30;    // angles

typedef _Float16 h8  __attribute__((ext_vector_type(8)));   // MFMA A/B frag (4 VGPR)
typedef _Float16 h4  __attribute__((ext_vector_type(4)));   // staged A half-frag
typedef float    f4  __attribute__((ext_vector_type(4)));   // MFMA C/D frag

// LDS row stride (halfs): 264 = 256+8 -> rows 528 B (16-B aligned), and b128
// reads land 8 words/bank (= hardware minimum). Used for BOTH refT and wmA.
constexpr int RT_LD = 264;
constexpr int WA_LD = 264;

// ---------------- R20: M-split + B-in-registers + LDS union -----------------
// Empirical rule from R12..R19 bisects: staged-LDS GEMM passes ONLY in the
// R18 shape (all ds_writes -> one barrier -> read-only K-loop). R16 (dbuf),
// R17 (2 barriers/step), R19 (wave-private, no barriers) ALL fail ~0.05
// absmax when LDS writes sit inside the unrolled MFMA loop; R18 (monolithic
// pre-stage) passes at 0.0039. R18's defect was 149 KB LDS -> 1 block/CU
// (8% occ, 54 us). R20 keeps the proven shape and fixes the footprint:
//   * M-SPLIT: grid 1200 = (trace, mhalf). Each block computes 128 out rows
//     (8 m-tiles, 2 per wave) -> stages only 128 wm rows. Unlike the R13/R15
//     ANGLE split, out rows are disjoint -> no write amplification.
//     Phase 1 (refT, all 30 angles) runs 2x per trace - cheap VALU.
//   * B-FRAGS IN REGISTERS: after the refT barrier, each lane loads its 16
//     B-fragments (32 VGPR) once; refT's LDS is then dead, so wmA UNIONs
//     onto the same memory. Barrier between the B-reads and the staging
//     writes makes the reuse safe (syncthreads drains lgkmcnt before
//     s_barrier). LDS total 67.8 KB -> 2 blocks/CU.
//   * Staging values BIT-IDENTICAL to R18 (row clamp 249, col zero-select
//     >=250, RNE f32->f16); coalesced 8-rows x 32-B global pattern (~16
//     lines/instr vs 64 for R12's lane->row A-gather = the L1-request
//     bottleneck this whole arc is attacking).
//   * K-loop: pure LDS reads + MFMA, zero barriers, zero global traffic.
// NO workspace, NO producer kernel (R8-R11 non-deterministic handoff).
__global__ __launch_bounds__(256, 2)
void zoep_fused(const float* __restrict__ vp,
                const float* __restrict__ vs,
                const float* __restrict__ rho,
                const float* __restrict__ theta,
                const float* __restrict__ wm,
                float* __restrict__ out)
{
    // Union: refT[32][RT_LD] (16.9 KB) lives here until B-frags are in regs;
    // wmA[128][WA_LD] (67.6 KB) overwrites it after the barrier.
    __shared__ alignas(16) _Float16 smem[128 * WA_LD];
    __shared__ float sth_s[32];
    __shared__ float cth_s[32];

    _Float16* const refT = smem;
    _Float16* const wmA  = smem;

    const int tid   = threadIdx.x;
    const int bid   = blockIdx.x;
    const int t     = bid >> 1;
    const int mhalf = bid & 1;
    const int mbase = mhalf * 128;    // global wm/out row base for this block

    if (tid < 32) {
        const float th = (tid < A) ? theta[tid] : 0.0f;
        sth_s[tid] = sinf(th);
        cth_s[tid] = cosf(th);
    }
    __syncthreads();

    // ---- Phase 1: thread owns interface k = tid (0..255) ---- (R12 verbatim)
    const int  k     = tid;
    const bool valid = (k < L - 1);
    const int  kc    = valid ? k : (L - 2);   // clamped: loads always in-bounds

    const float a1 = vp[kc * T + t];          // lane-distinct lines, 1 instr/array
    const float a2 = vp[(kc + 1) * T + t];
    const float b1 = vs[kc * T + t];
    const float b2 = vs[(kc + 1) * T + t];
    const float r1 = rho[kc * T + t];
    const float r2 = rho[(kc + 1) * T + t];

    const float ra1  = __builtin_amdgcn_rcpf(a1);
    const float rb1  = r1 * b1, rb2 = r2 * b2;
    const float ra1r = r1 * a1, ra2r = r2 * a2;

#pragma unroll 2
    for (int a = 0; a < A; ++a) {
        const float sth = sth_s[a];           // LDS broadcast (uniform a)
        const float cth = cth_s[a];

        const float p   = sth * ra1;
        const float s2  = p * a2;             // |.| <= 0.84 < 1 (input ranges)
        const float c2  = sqrtf(1.0f - s2 * s2);
        const float sp1 = p * b1;
        const float cp1 = sqrtf(1.0f - sp1 * sp1);
        const float sp2 = p * b2;
        const float cp2 = sqrtf(1.0f - sp2 * sp2);

        const float k1 = 1.0f - 2.0f * sp1 * sp1;
        const float k2 = 1.0f - 2.0f * sp2 * sp2;
        const float q1 = rb1 * k1;
        const float q2 = rb2 * k2;
        const float P1 = ra1r * k1;
        const float P2 = ra2r * k2;
        const float u1 = 2.0f * rb1 * sp1;
        const float u2 = 2.0f * rb2 * sp2;
        const float S1 = u1 * cp1;
        const float S2 = u2 * cp2;
        const float g1 = u1 * cth;
        const float g2 = u2 * c2;

        // M (row-major)
        const float m00 = -sth, m01 = -cp1, m02 = s2,  m03 = cp2;
        const float m10 =  cth, m11 = -sp1, m12 = c2,  m13 = -sp2;
        const float m20 =  g1,  m21 =  q1,  m22 = g2,  m23 = q2;
        const float m30 = -P1,  m31 =  S1,  m32 = P2,  m33 = -S2;

        // 2x2 minors: s* rows{0,1}, c* rows{2,3}
        const float s3v = m01 * m12 - m11 * m02;
        const float s4v = m01 * m13 - m11 * m03;
        const float s5v = m02 * m13 - m12 * m03;
        const float c3v = m21 * m32 - m31 * m22;
        const float c4v = m21 * m33 - m31 * m23;
        const float c5v = m22 * m33 - m32 * m23;
        const float s0v = m00 * m11 - m10 * m01;
        const float s1v = m00 * m12 - m10 * m02;
        const float s2v = m00 * m13 - m10 * m03;
        const float c0v = m20 * m31 - m30 * m21;
        const float c1v = m20 * m32 - m30 * m22;
        const float c2v = m20 * m33 - m30 * m23;

        const float detM = s0v*c5v - s1v*c4v + s2v*c3v
                         + s3v*c2v - s4v*c1v + s5v*c0v;
        const float A0 = m11*c5v - m12*c4v + m13*c3v;   // minor(0,0)
        const float A3 = m21*s5v - m22*s4v + m23*s3v;   // minor(3,0)

        const float num = m00 * A0 - m30 * A3;
        const float res = 1.0f - 2.0f * num * __builtin_amdgcn_rcpf(detM);

        refT[a * RT_LD + k] = (_Float16)(valid ? res : 0.0f);
    }
    // zero pad rows a = 30, 31 (column k)
    refT[30 * RT_LD + k] = (_Float16)0.0f;
    refT[31 * RT_LD + k] = (_Float16)0.0f;
    __syncthreads();   // refT published

    // ---- B-fragments -> registers (verified layout: B[k=quad*8+j][n=lane&15])
    const int w    = tid >> 6;       // wave 0..3
    const int lane = tid & 63;
    const int quad = lane >> 4;      // 0..3
    const int n16  = lane & 15;

    h8 bf[8][2];                     // 16 x h8 = 32 VGPR, static-indexed
#pragma unroll
    for (int ks = 0; ks < 8; ++ks) {
        const int kofs = ks * 32 + quad * 8;
        bf[ks][0] = *(const h8*)&refT[ n16       * RT_LD + kofs];
        bf[ks][1] = *(const h8*)&refT[(16 + n16) * RT_LD + kofs];
    }
    __syncthreads();   // all refT reads complete -> smem reusable

    // ---- Stage wm rows [mbase, mbase+128) -> wmA (R18 staging, p<4) ---------
    // wmA[r][c] = f16(wm[clamp(mbase+r)][c]) with zero-select for c>=250.
    {
        const int cg = tid & 7;      // col group (4 cols) 0..7
        const int r0 = tid >> 3;     // row 0..31 within each 32-row pass
#pragma unroll
        for (int cs = 0; cs < 8; ++cs) {
#pragma unroll
            for (int p = 0; p < 4; ++p) {
                const int r  = p * 32 + r0;                 // local row 0..127
                const int g  = mbase + r;                   // global wm row
                const int gc = (g < L) ? g : (L - 1);
                const int c0 = cs * 32 + cg * 4;            // 0..252
                const int c0c = (c0     <= L - 2) ? c0     : (L - 2);
                const int c1c = (c0 + 2 <= L - 2) ? c0 + 2 : (L - 2);
                const float2 f0 = *(const float2*)(wm + gc * L + c0c); // 8-B ok
                const float2 f1 = *(const float2*)(wm + gc * L + c1c);
                h4 v;
                v[0] = (_Float16)((c0     < L) ? f0.x : 0.0f);
                v[1] = (_Float16)((c0 + 1 < L) ? f0.y : 0.0f);
                v[2] = (_Float16)((c0 + 2 < L) ? f1.x : 0.0f);
                v[3] = (_Float16)((c0 + 3 < L) ? f1.y : 0.0f);
                *(h4*)&wmA[r * WA_LD + c0] = v;   // 8-B aligned ds_write_b64
            }
        }
    }
    __syncthreads();   // wmA published; NO LDS writes after this point

    // ---- K-loop: read-only LDS + MFMA (R18-proven shape), no barriers -------
    // A[m=lane&15][k=quad*8+j]; C/D[row=quad*4+reg][col=lane&15].
    f4 acc[2][2];
#pragma unroll
    for (int mi = 0; mi < 2; ++mi)
#pragma unroll
        for (int nt = 0; nt < 2; ++nt) acc[mi][nt] = (f4){0.f, 0.f, 0.f, 0.f};

#pragma unroll
    for (int ks = 0; ks < 8; ++ks) {                 // K = 8 x 32
        const int kofs = ks * 32 + quad * 8;
#pragma unroll
        for (int mi = 0; mi < 2; ++mi) {
            const int mloc = (w * 2 + mi) * 16 + n16;            // 0..127
            const h8 af = *(const h8*)&wmA[mloc * WA_LD + kofs]; // b128
            acc[mi][0] = __builtin_amdgcn_mfma_f32_16x16x32_f16(af, bf[ks][0], acc[mi][0], 0, 0, 0);
            acc[mi][1] = __builtin_amdgcn_mfma_f32_16x16x32_f16(af, bf[ks][1], acc[mi][1], 0, 0, 0);
        }
    }

    // ---- Epilogue: D[row=quad*4+r][col=n16] -> out[t][l][a] -----------------
    float* outt = out + (size_t)t * (L * A);
#pragma unroll
    for (int mi = 0; mi < 2; ++mi) {
        const int lbase = mbase + (w * 2 + mi) * 16 + quad * 4;
#pragma unroll
        for (int nt = 0; nt < 2; ++nt) {
            const int a = nt * 16 + n16;
            if (a < A) {
#pragma unroll
                for (int r = 0; r < 4; ++r) {
                    const int l = lbase + r;
                    if (l < L) outt[l * A + a] = acc[mi][nt][r];
                }
            }
        }
    }
}

extern "C" void kernel_launch(void* const* d_in, const int* in_sizes, int n_in,
                              void* d_out, int out_size, void* d_ws, size_t ws_size,
                              hipStream_t stream) {
    (void)in_sizes; (void)n_in; (void)out_size; (void)d_ws; (void)ws_size;
    const float* vp    = (const float*)d_in[0];
    const float* vs    = (const float*)d_in[1];
    const float* rho   = (const float*)d_in[2];
    const float* theta = (const float*)d_in[3];
    const float* wm    = (const float*)d_in[4];
    float* out = (float*)d_out;

    // Grid 2*T: block b -> trace b>>1, m-half b&1 (disjoint out rows -> no
    // write amplification, unlike the angle split).
    zoep_fused<<<dim3(2 * T), dim3(256), 0, stream>>>(vp, vs, rho, theta, wm, out);
}

// Round 8
// 99.754 us; speedup vs baseline: 1.1354x; 1.1306x over previous
//
#include <hip/hip_runtime.h>

// Problem constants (from reference)
constexpr int L  = 250;   // layers
constexpr int T  = 600;   // traces
constexpr int A  = 30;    // angles

typedef _Float16 h8  __attribute__((ext_vector_type(8)));   // MFMA A/B frag (4 VGPR)
typedef float    f4  __attribute__((ext_vector_type(4)));   // MFMA C/D frag
// 8-B-aligned float4: odd wm rows are 1000 B apart -> row base = 8 mod 16.
// dwordx4 needs only 4-B alignment in HW; aligned(8) typedef tells LLVM.
typedef float    f4u __attribute__((ext_vector_type(4), aligned(8)));

// refT LDS row stride (halfs): 264 = 256+8 -> 16-B aligned rows, 2-way-free banks
constexpr int RT_LD = 264;

// ---------------- R22: R12 + dwordx4 A-fragment loads ------------------------
// Locked constraints (R13-R21 bisects): single kernel (d_ws producer handoff
// fails ~0.035-0.07, R8-R11/R21); no ds_writes inside the K-loop (R16/R17/R19
// all fail ~0.05 regardless of sync discipline); LDS staging only in the R18
// all-writes-before-one-barrier shape, and it costs >= the scatter it
// replaces (R18 54 us, R20 55.8 us); angle-split doubles WRITE_SIZE (R13/R15).
//
// Transport model (explains R12/R15/R18/R20): A-frag gather is lane->row
// scattered (1000-B stride): 4x float2 per fragment = 128 scattered wave-
// instrs x 64 line-lookups per wave. R15 doubled occupancy -> flat => RATE-
// bound, not latency-bound. Only in-constraint lever: fewer scattered instrs
// for the same 32 B/lane -> 2x dwordx4 (the HW floor). Halves scattered
// instrs AND line-lookups. ks<=6 cols <= 223 < 250: no clamps (R15-proven);
// ks=7 keeps R12's clamped-float2 path verbatim. wrow hoist = R15 (passed).
// Everything else is byte-verbatim R12 (proven twice, absmax 0.0039).
// NO workspace, NO producer kernel.
__global__ __launch_bounds__(256)
void zoep_fused(const float* __restrict__ vp,
                const float* __restrict__ vs,
                const float* __restrict__ rho,
                const float* __restrict__ theta,
                const float* __restrict__ wm,
                float* __restrict__ out)
{
    __shared__ _Float16 refT[32 * RT_LD];   // 16.5 KB: refT[a][k]
    __shared__ float sth_s[32];
    __shared__ float cth_s[32];

    const int tid = threadIdx.x;
    const int t   = blockIdx.x;

    if (tid < 32) {
        const float th = (tid < A) ? theta[tid] : 0.0f;
        sth_s[tid] = sinf(th);
        cth_s[tid] = cosf(th);
    }
    __syncthreads();

    // ---- Phase 1: thread owns interface k = tid (0..255) ---- (R12 verbatim)
    const int  k     = tid;
    const bool valid = (k < L - 1);
    const int  kc    = valid ? k : (L - 2);   // clamped: loads always in-bounds

    const float a1 = vp[kc * T + t];          // lane-distinct lines, 1 instr/array
    const float a2 = vp[(kc + 1) * T + t];
    const float b1 = vs[kc * T + t];
    const float b2 = vs[(kc + 1) * T + t];
    const float r1 = rho[kc * T + t];
    const float r2 = rho[(kc + 1) * T + t];

    const float ra1  = __builtin_amdgcn_rcpf(a1);
    const float rb1  = r1 * b1, rb2 = r2 * b2;
    const float ra1r = r1 * a1, ra2r = r2 * a2;

#pragma unroll 2
    for (int a = 0; a < A; ++a) {
        const float sth = sth_s[a];           // LDS broadcast (uniform a)
        const float cth = cth_s[a];

        const float p   = sth * ra1;
        const float s2  = p * a2;             // |.| <= 0.84 < 1 (input ranges)
        const float c2  = sqrtf(1.0f - s2 * s2);
        const float sp1 = p * b1;
        const float cp1 = sqrtf(1.0f - sp1 * sp1);
        const float sp2 = p * b2;
        const float cp2 = sqrtf(1.0f - sp2 * sp2);

        const float k1 = 1.0f - 2.0f * sp1 * sp1;
        const float k2 = 1.0f - 2.0f * sp2 * sp2;
        const float q1 = rb1 * k1;
        const float q2 = rb2 * k2;
        const float P1 = ra1r * k1;
        const float P2 = ra2r * k2;
        const float u1 = 2.0f * rb1 * sp1;
        const float u2 = 2.0f * rb2 * sp2;
        const float S1 = u1 * cp1;
        const float S2 = u2 * cp2;
        const float g1 = u1 * cth;
        const float g2 = u2 * c2;

        // M (row-major)
        const float m00 = -sth, m01 = -cp1, m02 = s2,  m03 = cp2;
        const float m10 =  cth, m11 = -sp1, m12 = c2,  m13 = -sp2;
        const float m20 =  g1,  m21 =  q1,  m22 = g2,  m23 = q2;
        const float m30 = -P1,  m31 =  S1,  m32 = P2,  m33 = -S2;

        // 2x2 minors: s* rows{0,1}, c* rows{2,3}
        const float s3v = m01 * m12 - m11 * m02;
        const float s4v = m01 * m13 - m11 * m03;
        const float s5v = m02 * m13 - m12 * m03;
        const float c3v = m21 * m32 - m31 * m22;
        const float c4v = m21 * m33 - m31 * m23;
        const float c5v = m22 * m33 - m32 * m23;
        const float s0v = m00 * m11 - m10 * m01;
        const float s1v = m00 * m12 - m10 * m02;
        const float s2v = m00 * m13 - m10 * m03;
        const float c0v = m20 * m31 - m30 * m21;
        const float c1v = m20 * m32 - m30 * m22;
        const float c2v = m20 * m33 - m30 * m23;

        const float detM = s0v*c5v - s1v*c4v + s2v*c3v
                         + s3v*c2v - s4v*c1v + s5v*c0v;
        const float A0 = m11*c5v - m12*c4v + m13*c3v;   // minor(0,0)
        const float A3 = m21*s5v - m22*s4v + m23*s3v;   // minor(3,0)

        const float num = m00 * A0 - m30 * A3;
        const float res = 1.0f - 2.0f * num * __builtin_amdgcn_rcpf(detM);

        refT[a * RT_LD + k] = (_Float16)(valid ? res : 0.0f);
    }
    // zero pad rows a = 30, 31 (column k)
    refT[30 * RT_LD + k] = (_Float16)0.0f;
    refT[31 * RT_LD + k] = (_Float16)0.0f;
    __syncthreads();

    // ---- Phase 2: MFMA GEMM. wave w owns m-tiles w*4..w*4+3, both n-tiles.
    // Verified layouts (R12): A[m=lane&15][k=quad*8+j], B[k=quad*8+j][n=lane&15],
    // C/D[row=quad*4+reg][col=lane&15].
    const int w    = tid >> 6;       // wave 0..3
    const int lane = tid & 63;
    const int quad = lane >> 4;      // 0..3
    const int n16  = lane & 15;

    f4 acc[4][2];
#pragma unroll
    for (int mi = 0; mi < 4; ++mi)
#pragma unroll
        for (int nt = 0; nt < 2; ++nt) acc[mi][nt] = (f4){0.f, 0.f, 0.f, 0.f};

    // Hoisted, clamped wm row pointers (R15-proven; store-masked at epilogue)
    const float* wrow[4];
#pragma unroll
    for (int mi = 0; mi < 4; ++mi) {
        const int m = (w * 4 + mi) * 16 + n16;        // logical wm row 0..255
        wrow[mi] = wm + ((m < L) ? m : (L - 1)) * L;
    }

    // ks = 0..6: cols kofs..kofs+7 <= 223 < 250 -> no clamps; 2x dwordx4
    // (8-B aligned: row base 0/8 mod 16, kofs multiple of 32 B).
#pragma unroll
    for (int ks = 0; ks < 7; ++ks) {
        const int kofs = ks * 32 + quad * 8;
        const h8 b0 = *(const h8*)&refT[ n16       * RT_LD + kofs];
        const h8 b1 = *(const h8*)&refT[(16 + n16) * RT_LD + kofs];
#pragma unroll
        for (int mi = 0; mi < 4; ++mi) {
            const f4u g0 = *(const f4u*)(wrow[mi] + kofs);
            const f4u g1 = *(const f4u*)(wrow[mi] + kofs + 4);
            const h8 af = { (_Float16)g0[0], (_Float16)g0[1],
                            (_Float16)g0[2], (_Float16)g0[3],
                            (_Float16)g1[0], (_Float16)g1[1],
                            (_Float16)g1[2], (_Float16)g1[3] };
            acc[mi][0] = __builtin_amdgcn_mfma_f32_16x16x32_f16(af, b0, acc[mi][0], 0, 0, 0);
            acc[mi][1] = __builtin_amdgcn_mfma_f32_16x16x32_f16(af, b1, acc[mi][1], 0, 0, 0);
        }
    }
    { // ks = 7: cols 224..255 - only quad==3 (248..255) partial. R12 boundary
      // path verbatim: pair-clamp keeps loads in wm[0..62499], zero-select
      // keeps cols >= 250 finite (they multiply zero refT columns).
        const int kofs = 224 + quad * 8;
        const h8 b0 = *(const h8*)&refT[ n16       * RT_LD + kofs];
        const h8 b1 = *(const h8*)&refT[(16 + n16) * RT_LD + kofs];
#pragma unroll
        for (int mi = 0; mi < 4; ++mi) {
            h8 af;
#pragma unroll
            for (int c = 0; c < 4; ++c) {
                const int col  = kofs + 2 * c;                    // even
                const int colc = (col <= L - 2) ? col : (L - 2);  // pair start <= 248
                const float2 f = *(const float2*)(wrow[mi] + colc); // 8-B aligned
                af[2 * c]     = (_Float16)((col     < L) ? f.x : 0.0f);
                af[2 * c + 1] = (_Float16)((col + 1 < L) ? f.y : 0.0f);
            }
            acc[mi][0] = __builtin_amdgcn_mfma_f32_16x16x32_f16(af, b0, acc[mi][0], 0, 0, 0);
            acc[mi][1] = __builtin_amdgcn_mfma_f32_16x16x32_f16(af, b1, acc[mi][1], 0, 0, 0);
        }
    }

    // ---- Epilogue: D[row=quad*4+r][col=n16] -> out[t][l][a] ---- (R12 verbatim)
    float* outt = out + (size_t)t * (L * A);
#pragma unroll
    for (int mi = 0; mi < 4; ++mi) {
        const int mbase = (w * 4 + mi) * 16 + quad * 4;
#pragma unroll
        for (int nt = 0; nt < 2; ++nt) {
            const int a = nt * 16 + n16;
            if (a < A) {
#pragma unroll
                for (int r = 0; r < 4; ++r) {
                    const int l = mbase + r;
                    if (l < L) outt[l * A + a] = acc[mi][nt][r];
                }
            }
        }
    }
}

extern "C" void kernel_launch(void* const* d_in, const int* in_sizes, int n_in,
                              void* d_out, int out_size, void* d_ws, size_t ws_size,
                              hipStream_t stream) {
    (void)in_sizes; (void)n_in; (void)out_size; (void)d_ws; (void)ws_size;
    const float* vp    = (const float*)d_in[0];
    const float* vs    = (const float*)d_in[1];
    const float* rho   = (const float*)d_in[2];
    const float* theta = (const float*)d_in[3];
    const float* wm    = (const float*)d_in[4];
    float* out = (float*)d_out;

    zoep_fused<<<dim3(T), dim3(256), 0, stream>>>(vp, vs, rho, theta, wm, out);
}